// Round 7
// baseline (148.560 us; speedup 1.0000x reference)
//
#include <hip/hip_runtime.h>
#include <hip/hip_bf16.h>
#include <math.h>

// Problem constants
#define NB    2048          // B
#define ACT   14
#define NC    128           // C
#define NH    32            // H
#define NNODE (NB*ACT)      // 28672
#define NEDGE (NB*ACT*ACT)  // 401408
#define NPAIR (NB*ACT*ACT)  // 401408 output rows (b, 196)

// ---------------------------------------------------------------------------
// init kernel: zero deg histogram, zero dummy y row, pack W1 [256x32]->Wp[128x64]
// ---------------------------------------------------------------------------
__global__ __launch_bounds__(256) void init_misc(
    int* __restrict__ deg, float* __restrict__ ydummy,
    const float* __restrict__ W1, float* __restrict__ Wp)
{
    int idx = blockIdx.x * 256 + threadIdx.x;          // 0 .. 28671
    if (idx < NNODE) deg[idx] = 0;
    if (idx < 128) ydummy[idx] = 0.f;
    if (idx < 128 * 64) {
        int k = idx >> 6, c = idx & 63;
        Wp[idx] = (c < 32) ? W1[k * 32 + c] : W1[(128 + k) * 32 + (c - 32)];
    }
}

// ---------------------------------------------------------------------------
// tiled fp32 GEMM, A [nrows x 128] @ W [128 x ncols] -> C [nrows x ncols]
// 64x64 tile, 256 threads, 4x4 register blocking, XOR-swizzled A tile in LDS.
// Optional per-row output scale (rowscale != nullptr -> C[r,:] *= rowscale[r]).
// ---------------------------------------------------------------------------
__global__ __launch_bounds__(256) void gemm_k128(
    const float* __restrict__ A, const float* __restrict__ W,
    float* __restrict__ C, int ncols, const float* __restrict__ rowscale)
{
    __shared__ float As[64 * 128];   // 32 KB
    __shared__ float Ws[128 * 64];   // 32 KB
    const int tid  = threadIdx.x;
    const int row0 = blockIdx.x * 64;
    const int col0 = blockIdx.y * 64;

    {
        const float4* Ag = (const float4*)(A + (size_t)row0 * 128);
#pragma unroll
        for (int it = 0; it < 8; ++it) {
            int idx = tid + it * 256;          // float4 index in tile
            int r = idx >> 5;
            int c = (idx & 31) << 2;           // float col, multiple of 4
            int cs = c ^ (((r >> 2) & 3) << 2);
            *((float4*)&As[r * 128 + cs]) = Ag[r * 32 + (c >> 2)];
        }
#pragma unroll
        for (int it = 0; it < 8; ++it) {
            int idx = tid + it * 256;
            int k = idx >> 4;
            int c = (idx & 15) << 2;
            *((float4*)&Ws[k * 64 + c]) =
                *((const float4*)&W[(size_t)k * ncols + col0 + c]);
        }
    }
    __syncthreads();

    const int tx = tid & 15;       // col group
    const int ty = tid >> 4;       // row group
    const int ri0 = ty * 4;

    float acc[4][4] = {};
    for (int k = 0; k < 128; k += 4) {
        float a_s[4][4];
        float w_s[4][4];
#pragma unroll
        for (int i = 0; i < 4; ++i) {
            int r = ri0 + i;
            *((float4*)&a_s[i][0]) =
                *((const float4*)&As[r * 128 + (k ^ (((r >> 2) & 3) << 2))]);
        }
#pragma unroll
        for (int kk = 0; kk < 4; ++kk) {
            *((float4*)&w_s[kk][0]) =
                *((const float4*)&Ws[(k + kk) * 64 + tx * 4]);
        }
#pragma unroll
        for (int kk = 0; kk < 4; ++kk)
#pragma unroll
            for (int i = 0; i < 4; ++i)
#pragma unroll
                for (int j = 0; j < 4; ++j)
                    acc[i][j] += a_s[i][kk] * w_s[kk][j];
    }

#pragma unroll
    for (int i = 0; i < 4; ++i) {
        float s = rowscale ? rowscale[row0 + ri0 + i] : 1.0f;
        float4 v = make_float4(acc[i][0] * s, acc[i][1] * s,
                               acc[i][2] * s, acc[i][3] * s);
        *((float4*)&C[(size_t)(row0 + ri0 + i) * ncols + col0 + tx * 4]) = v;
    }
}

// ---------------------------------------------------------------------------
// degree histogram (int atomics)
// ---------------------------------------------------------------------------
__global__ void deg_count(const int* __restrict__ dst, int* __restrict__ deg)
{
    int e = blockIdx.x * blockDim.x + threadIdx.x;
    if (e < NEDGE) atomicAdd(&deg[dst[e]], 1);
}

// ---------------------------------------------------------------------------
// single-block exclusive scan of deg -> cursor (start offsets); also dinv.
// 28672 = 1024 threads x 28 elements each.
// ---------------------------------------------------------------------------
__global__ __launch_bounds__(1024) void scan_dinv(
    const int* __restrict__ deg, int* __restrict__ cursor,
    float* __restrict__ dinv)
{
    __shared__ int part[1024];
    const int t = threadIdx.x;
    const int base = t * 28;
    int local[28];
    int s = 0;
#pragma unroll
    for (int i = 0; i < 28; ++i) { local[i] = s; s += deg[base + i]; }
    part[t] = s;
    __syncthreads();
    int own = s;
    for (int off = 1; off < 1024; off <<= 1) {
        int tmp = (t >= off) ? part[t - off] : 0;
        __syncthreads();
        part[t] += tmp;
        __syncthreads();
    }
    int prefix = part[t] - own;   // exclusive prefix of this thread's chunk
#pragma unroll
    for (int i = 0; i < 28; ++i) {
        cursor[base + i] = prefix + local[i];
        dinv[base + i] = rsqrtf((float)deg[base + i] + 1.0f);
    }
}

// ---------------------------------------------------------------------------
// CSR fill: csr_src[pos] = src[e], pos = cursor[dst[e]]++  (int atomics)
// ---------------------------------------------------------------------------
__global__ void csr_fill(const int* __restrict__ src, const int* __restrict__ dst,
                         int* __restrict__ cursor, int* __restrict__ csr_src)
{
    int e = blockIdx.x * blockDim.x + threadIdx.x;
    if (e < NEDGE) {
        int pos = atomicAdd(&cursor[dst[e]], 1);
        csr_src[pos] = src[e];
    }
}

// ---------------------------------------------------------------------------
// gather aggregation + GCN epilogue, fused:
//   x[d] = relu(dinv[d] * (y[d] + sum_{e->d} y[src]) + bias) + state[d]
// ---------------------------------------------------------------------------
__global__ __launch_bounds__(256) void gather_agg(
    const int* __restrict__ csr_src, const int* __restrict__ cursor,
    const int* __restrict__ deg, const float* __restrict__ y,
    const float* __restrict__ dinv, const float* __restrict__ bias,
    const float* __restrict__ state, float* __restrict__ xout)
{
    const int lane = threadIdx.x & 31;
    const int d = (blockIdx.x * 256 + threadIdx.x) >> 5;   // node id
    if (d >= NNODE) return;

    const int cnt = deg[d];
    const int end = cursor[d];
    const int start = end - cnt;

    float4 acc = ((const float4*)(y + (size_t)d * NC))[lane];  // self loop
    for (int base = 0; base < cnt; base += 32) {
        int rem = cnt - base;
        int m = rem < 32 ? rem : 32;
        int sv = (lane < m) ? csr_src[start + base + lane] : NNODE; // zero row
        int mm = (m + 3) & ~3;
        for (int j = 0; j < mm; j += 4) {
            int s0 = __shfl(sv, j + 0, 32);
            int s1 = __shfl(sv, j + 1, 32);
            int s2 = __shfl(sv, j + 2, 32);
            int s3 = __shfl(sv, j + 3, 32);
            float4 v0 = ((const float4*)(y + (size_t)s0 * NC))[lane];
            float4 v1 = ((const float4*)(y + (size_t)s1 * NC))[lane];
            float4 v2 = ((const float4*)(y + (size_t)s2 * NC))[lane];
            float4 v3 = ((const float4*)(y + (size_t)s3 * NC))[lane];
            acc.x += v0.x + v1.x + v2.x + v3.x;
            acc.y += v0.y + v1.y + v2.y + v3.y;
            acc.z += v0.z + v1.z + v2.z + v3.z;
            acc.w += v0.w + v1.w + v2.w + v3.w;
        }
    }

    const float dv = dinv[d];
    float4 b  = ((const float4*)bias)[lane];
    float4 st = ((const float4*)(state + (size_t)d * NC))[lane];
    float4 r;
    r.x = fmaxf(acc.x * dv + b.x, 0.f) + st.x;
    r.y = fmaxf(acc.y * dv + b.y, 0.f) + st.y;
    r.z = fmaxf(acc.z * dv + b.z, 0.f) + st.z;
    r.w = fmaxf(acc.w * dv + b.w, 0.f) + st.w;
    ((float4*)(xout + (size_t)d * NC))[lane] = r;
}

// ---------------------------------------------------------------------------
// pairs kernel: 2 pairs per thread, scalar-pipe weights, NO LDS.
// Pairs (2m, 2m+1) share batch b and row i (2m mod 14 is even, j <= 12), so
// the u row is loaded once and every W2 s_load feeds TWO v_fma (SGPR operand).
// Per-thread state: h2a[16]+h2b[16]... (2x32 accumulators) + 3 staged float4
// ~= 90 VGPR, no spill, two independent FMA chains for ILP.
// ---------------------------------------------------------------------------
__device__ __forceinline__ float softplusf(float z)
{
    return z > 0.f ? z + log1pf(expf(-z)) : log1pf(expf(z));
}

__global__ __launch_bounds__(256) void pairs2_sgpr_kernel(
    const float* __restrict__ uv, const float* __restrict__ W2,
    const float* __restrict__ b1, const float* __restrict__ b2,
    const float* __restrict__ muW, const float* __restrict__ mu_b,
    const float* __restrict__ sigW, const float* __restrict__ sig_b,
    float* __restrict__ out)
{
    const int m = blockIdx.x * 256 + threadIdx.x;   // 0 .. NPAIR/2-1
    const int b = m / 98;
    const int r = 2 * m - b * 196;                  // even, 0..194
    const int i = r / 14;
    const int j = r - i * 14;                       // even, <= 12

    const float* up  = uv + (size_t)(b * ACT + i) * 64;
    const float* vap = uv + (size_t)(b * ACT + j) * 64 + 32;
    const float* vbp = vap + 64;                    // pair j+1

    float h2a[32], h2b[32];
#pragma unroll
    for (int l = 0; l < 32; ++l) { h2a[l] = b2[l]; h2b[l] = h2a[l]; }

#pragma unroll 2
    for (int k4 = 0; k4 < 8; ++k4) {
        float4 uu = ((const float4*)up)[k4];
        float4 va = ((const float4*)vap)[k4];
        float4 vb = ((const float4*)vbp)[k4];
#pragma unroll
        for (int kk = 0; kk < 4; ++kk) {
            float uk = (kk == 0) ? uu.x : (kk == 1) ? uu.y :
                       (kk == 2) ? uu.z : uu.w;
            float vka = (kk == 0) ? va.x : (kk == 1) ? va.y :
                        (kk == 2) ? va.z : va.w;
            float vkb = (kk == 0) ? vb.x : (kk == 1) ? vb.y :
                        (kk == 2) ? vb.z : vb.w;
            float bb = b1[k4 * 4 + kk];             // uniform -> sgpr
            float za = uk + vka + bb;
            float zb = uk + vkb + bb;
            float ha = za > 0.f ? za : 0.01f * za;
            float hb = zb > 0.f ? zb : 0.01f * zb;
            const float* wrow = W2 + (k4 * 4 + kk) * 32;
#pragma unroll
            for (int l = 0; l < 32; ++l) {
                float w = wrow[l];                  // s_load, feeds 2 FMAs
                h2a[l] += ha * w;
                h2b[l] += hb * w;
            }
        }
    }

    float mua = mu_b[0] + 1e-10f, mub = mua;
    float sga = sig_b[0],          sgb = sga;
#pragma unroll
    for (int l = 0; l < 32; ++l) {
        float mw = muW[l], sw = sigW[l];            // uniform -> sgpr
        float ha = h2a[l];
        ha = ha > 0.f ? ha : 0.01f * ha;
        mua += ha * mw;  sga += ha * sw;
        float hb = h2b[l];
        hb = hb > 0.f ? hb : 0.01f * hb;
        mub += hb * mw;  sgb += hb * sw;
    }
    const int p0 = 2 * m;
    out[p0]             = softplusf(mua);
    out[p0 + 1]         = softplusf(mub);
    out[NPAIR + p0]     = expf(fminf(fmaxf(sga, -20.f), 2.f));
    out[NPAIR + p0 + 1] = expf(fminf(fmaxf(sgb, -20.f), 2.f));
}

// ---------------------------------------------------------------------------
// launch
// ---------------------------------------------------------------------------
extern "C" void kernel_launch(void* const* d_in, const int* in_sizes, int n_in,
                              void* d_out, int out_size, void* d_ws, size_t ws_size,
                              hipStream_t stream)
{
    const float* state  = (const float*)d_in[0];
    const float* conv_W = (const float*)d_in[1];
    const float* conv_b = (const float*)d_in[2];
    const float* lin1_W = (const float*)d_in[3];
    const float* lin1_b = (const float*)d_in[4];
    const float* lin2_W = (const float*)d_in[5];
    const float* lin2_b = (const float*)d_in[6];
    const float* mu_W   = (const float*)d_in[7];
    const float* mu_b   = (const float*)d_in[8];
    const float* sig_W  = (const float*)d_in[9];
    const float* sig_b  = (const float*)d_in[10];
    const int*   eidx   = (const int*)d_in[11];
    const int* e_src = eidx;
    const int* e_dst = eidx + NEDGE;

    float* out = (float*)d_out;

    // workspace layout (floats)
    float* ws = (float*)d_ws;
    float* y     = ws;                               // (N+1)*128; row N = zeros
    float* x     = y + (size_t)(NNODE + 1) * 128;    // N*128
    float* dinv  = x + (size_t)NNODE * 128;          // N
    int*   deg   = (int*)(dinv + NNODE);             // N
    int*   cursor= deg + NNODE;                      // N
    int*   csrs  = cursor + NNODE;                   // E
    float* Wp    = (float*)(csrs + NEDGE);           // 128*64
    float* uvb   = Wp + 128 * 64;                    // uv [N x 64]

    // init: deg=0, y dummy row=0, Wp packed
    init_misc<<<(NNODE + 255) / 256, 256, 0, stream>>>(
        deg, y + (size_t)NNODE * 128, lin1_W, Wp);

    // CSR build
    deg_count<<<NEDGE / 256, 256, 0, stream>>>(e_dst, deg);
    scan_dinv<<<1, 1024, 0, stream>>>(deg, cursor, dinv);
    csr_fill<<<NEDGE / 256, 256, 0, stream>>>(e_src, e_dst, cursor, csrs);

    // y = (state @ conv_W) * dinv[row]
    gemm_k128<<<dim3(NNODE / 64, 2), 256, 0, stream>>>(state, conv_W, y, 128, dinv);

    // x = relu(dinv*(y_self + sum y[src]) + b) + state
    gather_agg<<<(NNODE * 32) / 256, 256, 0, stream>>>(
        csrs, cursor, deg, y, dinv, conv_b, state, x);

    // uv = x @ [W1_top | W1_bot]
    gemm_k128<<<dim3(NNODE / 64, 1), 256, 0, stream>>>(x, Wp, uvb, 64, nullptr);

    // pairs -> output (2 pairs per thread, scalar-pipe weights)
    pairs2_sgpr_kernel<<<NPAIR / 512, 256, 0, stream>>>(
        uvb, lin2_W, lin1_b, lin2_b, mu_W, mu_b, sig_W, sig_b, out);
}

// Round 8
// 94.274 us; speedup vs baseline: 1.5758x; 1.5758x over previous
//
#include <hip/hip_runtime.h>
#include <hip/hip_bf16.h>
#include <math.h>

// Problem constants
#define NB    2048          // B
#define ACT   14
#define NC    128           // C
#define NH    32            // H
#define NNODE (NB*ACT)      // 28672
#define NEDGE (NB*ACT*ACT)  // 401408
#define NPAIR (NB*ACT*ACT)  // 401408 output rows (b, 196)
#define BCAP  64            // bucket capacity per node (Poisson(14), P(>64)~1e-22)

// bf16 helpers (RNE pack, cheap unpack)
__device__ __forceinline__ unsigned short f2bf(float f)
{
    unsigned u = __float_as_uint(f);
    return (unsigned short)((u + 0x7fff + ((u >> 16) & 1)) >> 16);
}
__device__ __forceinline__ float bfl(unsigned v) { return __uint_as_float(v << 16); }
__device__ __forceinline__ float bfh(unsigned v) { return __uint_as_float(v & 0xffff0000u); }

// ---------------------------------------------------------------------------
// init kernel: zero cnt histogram, zero dummy y row (bf16), pack W1->Wp
// ---------------------------------------------------------------------------
__global__ __launch_bounds__(256) void init_misc(
    int* __restrict__ cnt, unsigned short* __restrict__ ydummy,
    const float* __restrict__ W1, float* __restrict__ Wp)
{
    int idx = blockIdx.x * 256 + threadIdx.x;          // 0 .. 28671
    if (idx < NNODE) cnt[idx] = 0;
    if (idx < 128) ydummy[idx] = 0;
    if (idx < 128 * 64) {
        int k = idx >> 6, c = idx & 63;
        Wp[idx] = (c < 32) ? W1[k * 32 + c] : W1[(128 + k) * 32 + (c - 32)];
    }
}

// ---------------------------------------------------------------------------
// bucket fill: slot = cnt[dst]++; bucket[dst*64+slot] = src   (int atomics)
// ---------------------------------------------------------------------------
__global__ void bucket_fill(const int* __restrict__ src, const int* __restrict__ dst,
                            int* __restrict__ cnt, int* __restrict__ bucket)
{
    int e = blockIdx.x * blockDim.x + threadIdx.x;
    if (e < NEDGE) {
        int d = dst[e];
        int slot = atomicAdd(&cnt[d], 1);
        if (slot < BCAP) bucket[(size_t)d * BCAP + slot] = src[e];
    }
}

// ---------------------------------------------------------------------------
// GEMM1: y[r,:] = (A[r,:] @ W) * rsqrt(cnt[r]+1), output bf16.
// A [nrows x 128] @ W [128 x 128]; 64x64 tile, 4x4 register blocking.
// ---------------------------------------------------------------------------
__global__ __launch_bounds__(256) void gemm_k128_bf16(
    const float* __restrict__ A, const float* __restrict__ W,
    unsigned short* __restrict__ C, int ncols, const int* __restrict__ cnt)
{
    __shared__ float As[64 * 128];   // 32 KB
    __shared__ float Ws[128 * 64];   // 32 KB
    const int tid  = threadIdx.x;
    const int row0 = blockIdx.x * 64;
    const int col0 = blockIdx.y * 64;

    {
        const float4* Ag = (const float4*)(A + (size_t)row0 * 128);
#pragma unroll
        for (int it = 0; it < 8; ++it) {
            int idx = tid + it * 256;
            int r = idx >> 5;
            int c = (idx & 31) << 2;
            int cs = c ^ (((r >> 2) & 3) << 2);
            *((float4*)&As[r * 128 + cs]) = Ag[r * 32 + (c >> 2)];
        }
#pragma unroll
        for (int it = 0; it < 8; ++it) {
            int idx = tid + it * 256;
            int k = idx >> 4;
            int c = (idx & 15) << 2;
            *((float4*)&Ws[k * 64 + c]) =
                *((const float4*)&W[(size_t)k * ncols + col0 + c]);
        }
    }
    __syncthreads();

    const int tx = tid & 15;
    const int ty = tid >> 4;
    const int ri0 = ty * 4;

    float acc[4][4] = {};
    for (int k = 0; k < 128; k += 4) {
        float a_s[4][4];
        float w_s[4][4];
#pragma unroll
        for (int i = 0; i < 4; ++i) {
            int r = ri0 + i;
            *((float4*)&a_s[i][0]) =
                *((const float4*)&As[r * 128 + (k ^ (((r >> 2) & 3) << 2))]);
        }
#pragma unroll
        for (int kk = 0; kk < 4; ++kk) {
            *((float4*)&w_s[kk][0]) =
                *((const float4*)&Ws[(k + kk) * 64 + tx * 4]);
        }
#pragma unroll
        for (int kk = 0; kk < 4; ++kk)
#pragma unroll
            for (int i = 0; i < 4; ++i)
#pragma unroll
                for (int j = 0; j < 4; ++j)
                    acc[i][j] += a_s[i][kk] * w_s[kk][j];
    }

#pragma unroll
    for (int i = 0; i < 4; ++i) {
        float s = rsqrtf((float)cnt[row0 + ri0 + i] + 1.0f);
        ushort4 o;
        o.x = f2bf(acc[i][0] * s);
        o.y = f2bf(acc[i][1] * s);
        o.z = f2bf(acc[i][2] * s);
        o.w = f2bf(acc[i][3] * s);
        *((ushort4*)&C[(size_t)(row0 + ri0 + i) * ncols + col0 + tx * 4]) = o;
    }
}

// ---------------------------------------------------------------------------
// GEMM2 (fp32 out): uv = x @ Wp, ncols=64
// ---------------------------------------------------------------------------
__global__ __launch_bounds__(256) void gemm_k128(
    const float* __restrict__ A, const float* __restrict__ W,
    float* __restrict__ C, int ncols)
{
    __shared__ float As[64 * 128];
    __shared__ float Ws[128 * 64];
    const int tid  = threadIdx.x;
    const int row0 = blockIdx.x * 64;
    const int col0 = blockIdx.y * 64;

    {
        const float4* Ag = (const float4*)(A + (size_t)row0 * 128);
#pragma unroll
        for (int it = 0; it < 8; ++it) {
            int idx = tid + it * 256;
            int r = idx >> 5;
            int c = (idx & 31) << 2;
            int cs = c ^ (((r >> 2) & 3) << 2);
            *((float4*)&As[r * 128 + cs]) = Ag[r * 32 + (c >> 2)];
        }
#pragma unroll
        for (int it = 0; it < 8; ++it) {
            int idx = tid + it * 256;
            int k = idx >> 4;
            int c = (idx & 15) << 2;
            *((float4*)&Ws[k * 64 + c]) =
                *((const float4*)&W[(size_t)k * ncols + col0 + c]);
        }
    }
    __syncthreads();

    const int tx = tid & 15;
    const int ty = tid >> 4;
    const int ri0 = ty * 4;

    float acc[4][4] = {};
    for (int k = 0; k < 128; k += 4) {
        float a_s[4][4];
        float w_s[4][4];
#pragma unroll
        for (int i = 0; i < 4; ++i) {
            int r = ri0 + i;
            *((float4*)&a_s[i][0]) =
                *((const float4*)&As[r * 128 + (k ^ (((r >> 2) & 3) << 2))]);
        }
#pragma unroll
        for (int kk = 0; kk < 4; ++kk) {
            *((float4*)&w_s[kk][0]) =
                *((const float4*)&Ws[(k + kk) * 64 + tx * 4]);
        }
#pragma unroll
        for (int kk = 0; kk < 4; ++kk)
#pragma unroll
            for (int i = 0; i < 4; ++i)
#pragma unroll
                for (int j = 0; j < 4; ++j)
                    acc[i][j] += a_s[i][kk] * w_s[kk][j];
    }

#pragma unroll
    for (int i = 0; i < 4; ++i) {
        float4 v = make_float4(acc[i][0], acc[i][1], acc[i][2], acc[i][3]);
        *((float4*)&C[(size_t)(row0 + ri0 + i) * ncols + col0 + tx * 4]) = v;
    }
}

// ---------------------------------------------------------------------------
// gather aggregation + GCN epilogue (bf16 y rows):
//   x[d] = relu(rsqrt(cnt[d]+1) * (y[d] + sum y[src]) + bias) + state[d]
// One 32-lane group per node; lane q owns channels [4q, 4q+4) (8B bf16 load).
// ---------------------------------------------------------------------------
__global__ __launch_bounds__(256) void gather_agg(
    const int* __restrict__ bucket, const int* __restrict__ cnt,
    const unsigned short* __restrict__ y, const float* __restrict__ bias,
    const float* __restrict__ state, float* __restrict__ xout)
{
    const int lane = threadIdx.x & 31;
    const int d = (blockIdx.x * 256 + threadIdx.x) >> 5;   // node id
    if (d >= NNODE) return;

    const int c_true = cnt[d];
    const int c = c_true < BCAP ? c_true : BCAP;

    uint2 sv0 = ((const uint2*)(y + (size_t)d * NC))[lane];  // self loop
    float4 acc;
    acc.x = bfl(sv0.x); acc.y = bfh(sv0.x);
    acc.z = bfl(sv0.y); acc.w = bfh(sv0.y);

    const int* brow = bucket + (size_t)d * BCAP;
    for (int base = 0; base < c; base += 32) {
        int rem = c - base;
        int m = rem < 32 ? rem : 32;
        int sv = (lane < m) ? brow[base + lane] : NNODE;   // zero row
        int mm = (m + 3) & ~3;
        for (int j = 0; j < mm; j += 4) {
            int s0 = __shfl(sv, j + 0, 32);
            int s1 = __shfl(sv, j + 1, 32);
            int s2 = __shfl(sv, j + 2, 32);
            int s3 = __shfl(sv, j + 3, 32);
            uint2 a0 = ((const uint2*)(y + (size_t)s0 * NC))[lane];
            uint2 a1 = ((const uint2*)(y + (size_t)s1 * NC))[lane];
            uint2 a2 = ((const uint2*)(y + (size_t)s2 * NC))[lane];
            uint2 a3 = ((const uint2*)(y + (size_t)s3 * NC))[lane];
            acc.x += bfl(a0.x) + bfl(a1.x) + bfl(a2.x) + bfl(a3.x);
            acc.y += bfh(a0.x) + bfh(a1.x) + bfh(a2.x) + bfh(a3.x);
            acc.z += bfl(a0.y) + bfl(a1.y) + bfl(a2.y) + bfl(a3.y);
            acc.w += bfh(a0.y) + bfh(a1.y) + bfh(a2.y) + bfh(a3.y);
        }
    }

    const float dv = rsqrtf((float)c_true + 1.0f);
    float4 b  = ((const float4*)bias)[lane];
    float4 st = ((const float4*)(state + (size_t)d * NC))[lane];
    float4 r;
    r.x = fmaxf(acc.x * dv + b.x, 0.f) + st.x;
    r.y = fmaxf(acc.y * dv + b.y, 0.f) + st.y;
    r.z = fmaxf(acc.z * dv + b.z, 0.f) + st.z;
    r.w = fmaxf(acc.w * dv + b.w, 0.f) + st.w;
    ((float4*)(xout + (size_t)d * NC))[lane] = r;
}

// ---------------------------------------------------------------------------
// pairs kernel, scalar-pipe weights: 1 pair per thread, NO LDS (round-6 best).
// ---------------------------------------------------------------------------
__device__ __forceinline__ float softplusf(float z)
{
    return z > 0.f ? z + log1pf(expf(-z)) : log1pf(expf(z));
}

__global__ __launch_bounds__(256) void pairs_sgpr_kernel(
    const float* __restrict__ uv, const float* __restrict__ W2,
    const float* __restrict__ b1, const float* __restrict__ b2,
    const float* __restrict__ muW, const float* __restrict__ mu_b,
    const float* __restrict__ sigW, const float* __restrict__ sig_b,
    float* __restrict__ out)
{
    const int gid = blockIdx.x * 256 + threadIdx.x;   // 0 .. NPAIR-1
    const int b = gid / 196;
    const int p = gid - b * 196;
    const int i = p / 14;
    const int j = p - i * 14;

    const float* up = uv + (size_t)(b * ACT + i) * 64;
    const float* vp = uv + (size_t)(b * ACT + j) * 64 + 32;

    float h2[32];
#pragma unroll
    for (int l = 0; l < 32; ++l) h2[l] = b2[l];       // uniform -> s_load

#pragma unroll 2
    for (int k4 = 0; k4 < 8; ++k4) {
        float4 uu = ((const float4*)up)[k4];
        float4 vv = ((const float4*)vp)[k4];
#pragma unroll
        for (int kk = 0; kk < 4; ++kk) {
            float uvk = (kk == 0) ? uu.x + vv.x :
                        (kk == 1) ? uu.y + vv.y :
                        (kk == 2) ? uu.z + vv.z : uu.w + vv.w;
            float z = uvk + b1[k4 * 4 + kk];          // b1 uniform -> sgpr
            float h1k = z > 0.f ? z : 0.01f * z;
            const float* wrow = W2 + (k4 * 4 + kk) * 32;
#pragma unroll
            for (int l = 0; l < 32; ++l)
                h2[l] += h1k * wrow[l];               // s_load + v_fma (sgpr src)
        }
    }

    float mu_acc = mu_b[0] + 1e-10f;
    float sg = sig_b[0];
#pragma unroll
    for (int l = 0; l < 32; ++l) {
        float h = h2[l];
        h = h > 0.f ? h : 0.01f * h;
        mu_acc += h * muW[l];
        sg += h * sigW[l];
    }
    out[gid]         = softplusf(mu_acc);
    out[NPAIR + gid] = expf(fminf(fmaxf(sg, -20.f), 2.f));
}

// ---------------------------------------------------------------------------
// launch
// ---------------------------------------------------------------------------
extern "C" void kernel_launch(void* const* d_in, const int* in_sizes, int n_in,
                              void* d_out, int out_size, void* d_ws, size_t ws_size,
                              hipStream_t stream)
{
    const float* state  = (const float*)d_in[0];
    const float* conv_W = (const float*)d_in[1];
    const float* conv_b = (const float*)d_in[2];
    const float* lin1_W = (const float*)d_in[3];
    const float* lin1_b = (const float*)d_in[4];
    const float* lin2_W = (const float*)d_in[5];
    const float* lin2_b = (const float*)d_in[6];
    const float* mu_W   = (const float*)d_in[7];
    const float* mu_b   = (const float*)d_in[8];
    const float* sig_W  = (const float*)d_in[9];
    const float* sig_b  = (const float*)d_in[10];
    const int*   eidx   = (const int*)d_in[11];
    const int* e_src = eidx;
    const int* e_dst = eidx + NEDGE;

    float* out = (float*)d_out;

    // workspace layout
    char* wsb = (char*)d_ws;
    unsigned short* y = (unsigned short*)wsb;                 // (N+1)*128 bf16
    char* p = wsb + (size_t)(NNODE + 1) * NC * sizeof(unsigned short);
    float* x = (float*)p;            p += (size_t)NNODE * NC * sizeof(float);
    int* cnt = (int*)p;              p += (size_t)NNODE * sizeof(int);
    int* bucket = (int*)p;           p += (size_t)NNODE * BCAP * sizeof(int);
    float* Wp = (float*)p;           p += 128 * 64 * sizeof(float);
    float* uvb = (float*)p;          // N*64 f32

    // init: cnt=0, y dummy row=0, Wp packed
    init_misc<<<(NNODE + 255) / 256, 256, 0, stream>>>(
        cnt, y + (size_t)NNODE * NC, lin1_W, Wp);

    // bucket CSR (no scan)
    bucket_fill<<<NEDGE / 256, 256, 0, stream>>>(e_src, e_dst, cnt, bucket);

    // y = (state @ conv_W) * rsqrt(cnt+1)   [bf16 out]
    gemm_k128_bf16<<<dim3(NNODE / 64, 2), 256, 0, stream>>>(
        state, conv_W, y, 128, cnt);

    // x = relu(dinv*(y_self + sum y[src]) + b) + state
    gather_agg<<<(NNODE * 32) / 256, 256, 0, stream>>>(
        bucket, cnt, y, conv_b, state, x);

    // uv = x @ [W1_top | W1_bot]
    gemm_k128<<<dim3(NNODE / 64, 1), 256, 0, stream>>>(x, Wp, uvb, 64);

    // pairs -> output (1 pair per thread, scalar-pipe weights)
    pairs_sgpr_kernel<<<NPAIR / 256, 256, 0, stream>>>(
        uvb, lin2_W, lin1_b, lin2_b, mu_W, mu_b, sig_W, sig_b, out);
}